// Round 8
// baseline (178.326 us; speedup 1.0000x reference)
//
#include <hip/hip_runtime.h>

constexpr int B = 32;
constexpr int N = 32 * 32 * 32 + 1;   // 32769
constexpr int K = 32 * 3 * 3;         // 288
constexpr int KH = K / 2;             // 144 per half

using i4 = __attribute__((ext_vector_type(4))) int;
using f4 = __attribute__((ext_vector_type(4))) float;
using h4 = __attribute__((ext_vector_type(4))) _Float16;

// ---------------------------------------------------------------------------
// Kernel 1: transpose + downconvert x (B,N) fp32 -> xT (N,B) fp16 (2.1 MB).
// ---------------------------------------------------------------------------
__global__ __launch_bounds__(256) void transpose_x_f16_kernel(
    const float* __restrict__ x, _Float16* __restrict__ xT) {
  __shared__ float tile[32][33];
  const int n0 = blockIdx.x * 32;
  const int t  = threadIdx.x;
  const int lb = t & 31;   // 0..31
  const int lr = t >> 5;   // 0..7
#pragma unroll
  for (int i = 0; i < 4; ++i) {
    const int b = lr + i * 8;
    const int n = n0 + lb;
    float v = 0.f;
    if (n < N) v = x[(size_t)b * N + n];   // coalesced over lb
    tile[lb][b] = v;
  }
  __syncthreads();
#pragma unroll
  for (int i = 0; i < 4; ++i) {
    const int nl = lr + i * 8;
    const int n  = n0 + nl;
    if (n < N) xT[(size_t)n * B + lb] = (_Float16)tile[nl][lb];
  }
}

// ---------------------------------------------------------------------------
// Kernel 2: gather-dot, K split x2 (blockIdx.y = half). For 32 n's:
//   yTh[n][b] = sum_{k in half} (float)xT16[cols[n,k]][b] * vals[n,k]
// cols half packed to u16 in LDS (9.2 KB). Grid 2050 blocks -> 8 blocks/CU
// (32 waves/CU, 100% theoretical occupancy) — the clean latency-hiding test.
// 8-lane group per n; lane owns 4 consecutive b; 32-bit voffset addressing.
// ---------------------------------------------------------------------------
__global__ __launch_bounds__(256, 8) void gather_dot_f16_u16_ks2_kernel(
    const _Float16* __restrict__ xT, const float* __restrict__ vals,
    const int* __restrict__ cols, float* __restrict__ yT) {
  __shared__ unsigned short scols[32 * KH];   // 9216 B
  const int t    = threadIdx.x;
  const int lane = t & 63;
  const int wave = t >> 6;
  const int g    = lane >> 3;        // 0..7 : n within wave
  const int bq   = lane & 7;         // 0..7 : b quad
  const int n0   = blockIdx.x * 32;
  const int q    = blockIdx.y;       // K half
  const int k0   = q * KH;

  // --- Stage cols half-slab as u16: 32 rows x 36 int4 = 1152 chunks. ---
  // 4 full rounds of 256 + half round (t < 128).
  {
    const long long last = (long long)N * K - 4;   // last valid int4 start
    unsigned int* sc32 = (unsigned int*)scols;
#pragma unroll
    for (int r = 0; r < 4; ++r) {
      const int c   = r * 256 + t;            // chunk id 0..1023
      const int row = c / 36;
      const int off = c - row * 36;           // int4 within the 144-int half
      long long gi = (long long)(n0 + row) * K + k0 + (long long)off * 4;
      if (gi > last) gi = last;               // clamp (tail block junk rows)
      const i4 w = *reinterpret_cast<const i4*>(cols + gi);
      const unsigned int p0 = (unsigned int)(w.x & 0xFFFF) | ((unsigned int)w.y << 16);
      const unsigned int p1 = (unsigned int)(w.z & 0xFFFF) | ((unsigned int)w.w << 16);
      sc32[c * 2]     = p0;
      sc32[c * 2 + 1] = p1;
    }
    if (t < 128) {                            // chunks 1024..1151
      const int c   = 1024 + t;
      const int row = c / 36;
      const int off = c - row * 36;
      long long gi = (long long)(n0 + row) * K + k0 + (long long)off * 4;
      if (gi > last) gi = last;
      const i4 w = *reinterpret_cast<const i4*>(cols + gi);
      const unsigned int p0 = (unsigned int)(w.x & 0xFFFF) | ((unsigned int)w.y << 16);
      const unsigned int p1 = (unsigned int)(w.z & 0xFFFF) | ((unsigned int)w.w << 16);
      sc32[c * 2]     = p0;
      sc32[c * 2 + 1] = p1;
    }
  }
  __syncthreads();

  const int nl = wave * 8 + g;
  const int n  = n0 + nl;
  if (n >= N) return;

  const unsigned short* __restrict__ srow = scols + nl * KH;
  const char* __restrict__ xTb  = (const char*)xT + bq * 8;   // per-lane base
  const char* __restrict__ vrow = (const char*)(vals + (size_t)n * K + k0);

  f4 acc0 = {0.f, 0.f, 0.f, 0.f};
  f4 acc1 = {0.f, 0.f, 0.f, 0.f};

  const int rot = g * 8;   // bank-spread rotation (KH % 8 == 0)

#pragma unroll 4
  for (int k = 0; k < KH; k += 8) {            // 18 iterations
    int kk = k + rot;
    if (kk >= KH) kk -= KH;

    const i4 cp = *reinterpret_cast<const i4*>(srow + kk);   // 8 packed cols
    const f4 v0 = *reinterpret_cast<const f4*>(vrow + kk * 4);
    const f4 v1 = *reinterpret_cast<const f4*>(vrow + kk * 4 + 16);

    const unsigned int w0 = (unsigned int)cp.x;
    const unsigned int w1 = (unsigned int)cp.y;
    const unsigned int w2 = (unsigned int)cp.z;
    const unsigned int w3 = (unsigned int)cp.w;
    const unsigned int o0 = (w0 << 6) & 0x3FFFC0u;
    const unsigned int o1 = (w0 >> 10) & 0x3FFFC0u;
    const unsigned int o2 = (w1 << 6) & 0x3FFFC0u;
    const unsigned int o3 = (w1 >> 10) & 0x3FFFC0u;
    const unsigned int o4 = (w2 << 6) & 0x3FFFC0u;
    const unsigned int o5 = (w2 >> 10) & 0x3FFFC0u;
    const unsigned int o6 = (w3 << 6) & 0x3FFFC0u;
    const unsigned int o7 = (w3 >> 10) & 0x3FFFC0u;

    const h4 x0 = *reinterpret_cast<const h4*>(xTb + o0);
    const h4 x1 = *reinterpret_cast<const h4*>(xTb + o1);
    const h4 x2 = *reinterpret_cast<const h4*>(xTb + o2);
    const h4 x3 = *reinterpret_cast<const h4*>(xTb + o3);
    const h4 x4 = *reinterpret_cast<const h4*>(xTb + o4);
    const h4 x5 = *reinterpret_cast<const h4*>(xTb + o5);
    const h4 x6 = *reinterpret_cast<const h4*>(xTb + o6);
    const h4 x7 = *reinterpret_cast<const h4*>(xTb + o7);

    acc0 += __builtin_convertvector(x0, f4) * v0.x;
    acc0 += __builtin_convertvector(x1, f4) * v0.y;
    acc0 += __builtin_convertvector(x2, f4) * v0.z;
    acc0 += __builtin_convertvector(x3, f4) * v0.w;
    acc1 += __builtin_convertvector(x4, f4) * v1.x;
    acc1 += __builtin_convertvector(x5, f4) * v1.y;
    acc1 += __builtin_convertvector(x6, f4) * v1.z;
    acc1 += __builtin_convertvector(x7, f4) * v1.w;
  }

  acc0 += acc1;
  *reinterpret_cast<f4*>(yT + (size_t)q * N * B + (size_t)n * B + bq * 4) = acc0;
}

// ---------------------------------------------------------------------------
// Kernel 3: y (B,N) = transpose(yT0 + yT1), partials (N,B).
// ---------------------------------------------------------------------------
__global__ __launch_bounds__(256) void transpose_y_sum2_kernel(
    const float* __restrict__ yT, float* __restrict__ y) {
  __shared__ float tile[32][33];
  const int n0 = blockIdx.x * 32;
  const int t  = threadIdx.x;
  const int lb = t & 31;
  const int lr = t >> 5;
  constexpr size_t NB = (size_t)N * B;
#pragma unroll
  for (int i = 0; i < 4; ++i) {
    const int nl = lr + i * 8;
    const int n  = n0 + nl;
    float v = 0.f;
    if (n < N) {
      const size_t idx = (size_t)n * B + lb;
      v = yT[idx] + yT[NB + idx];   // coalesced over lb
    }
    tile[nl][lb] = v;
  }
  __syncthreads();
#pragma unroll
  for (int i = 0; i < 4; ++i) {
    const int b = lr + i * 8;
    const int n = n0 + lb;
    if (n < N) y[(size_t)b * N + n] = tile[lb][b];  // coalesced over lb
  }
}

// ---------------------------------------------------------------------------
// Fallback (ws too small): direct strided gather, fp32, correct but slow.
// ---------------------------------------------------------------------------
__global__ __launch_bounds__(256) void gather_dot_fallback(
    const float* __restrict__ x, const float* __restrict__ vals,
    const int* __restrict__ cols, float* __restrict__ y) {
  const int t    = threadIdx.x;
  const int lane = t & 63;
  const int wave = t >> 6;
  const int g    = lane >> 3;
  const int bq   = lane & 7;
  const int n    = blockIdx.x * 32 + wave * 8 + g;
  if (n >= N) return;
  const int*   crow = cols + (size_t)n * K;
  const float* vrow = vals + (size_t)n * K;
  float4 acc = make_float4(0.f, 0.f, 0.f, 0.f);
  for (int k = 0; k < K; ++k) {
    const int   c = crow[k];
    const float v = vrow[k];
    acc.x += x[(size_t)(bq * 4 + 0) * N + c] * v;
    acc.y += x[(size_t)(bq * 4 + 1) * N + c] * v;
    acc.z += x[(size_t)(bq * 4 + 2) * N + c] * v;
    acc.w += x[(size_t)(bq * 4 + 3) * N + c] * v;
  }
  y[(size_t)(bq * 4 + 0) * N + n] = acc.x;
  y[(size_t)(bq * 4 + 1) * N + n] = acc.y;
  y[(size_t)(bq * 4 + 2) * N + n] = acc.z;
  y[(size_t)(bq * 4 + 3) * N + n] = acc.w;
}

extern "C" void kernel_launch(void* const* d_in, const int* in_sizes, int n_in,
                              void* d_out, int out_size, void* d_ws, size_t ws_size,
                              hipStream_t stream) {
  const float* x    = (const float*)d_in[0];   // x_affine (B,N)
  const float* vals = (const float*)d_in[1];   // (N,K)
  const int*   cols = (const int*)d_in[2];     // (N,K)
  float*       y    = (float*)d_out;           // (B,N)

  const size_t nb       = (size_t)N * B;
  const size_t xT_bytes = nb * sizeof(_Float16);              // 2.1 MB
  const size_t need     = xT_bytes + 2 * nb * sizeof(float);  // + 2 partials

  const int nblocks = (N + 31) / 32;   // 1025

  if (ws_size >= need) {
    _Float16* xT = (_Float16*)d_ws;
    float*    yT = (float*)((char*)d_ws + xT_bytes);   // 2 partials contiguous
    transpose_x_f16_kernel<<<nblocks, 256, 0, stream>>>(x, xT);
    dim3 grid(nblocks, 2);
    gather_dot_f16_u16_ks2_kernel<<<grid, 256, 0, stream>>>(xT, vals, cols, yT);
    transpose_y_sum2_kernel<<<nblocks, 256, 0, stream>>>(yT, y);
  } else {
    gather_dot_fallback<<<nblocks, 256, 0, stream>>>(x, vals, cols, y);
  }
}